// Round 5
// baseline (718.908 us; speedup 1.0000x reference)
//
#include <hip/hip_runtime.h>
#include <hip/hip_bf16.h>

#define DD 512
#define MM 64
#define HH 8
#define HDIM 64
#define NROWS 131072

typedef __bf16 bf16x8 __attribute__((ext_vector_type(8)));
typedef float f32x4 __attribute__((ext_vector_type(4)));

static __device__ __forceinline__ unsigned bfbits(float f) {
    union { float f; unsigned u; } x; x.f = f;
    unsigned r = x.u + 0x7fffu + ((x.u >> 16) & 1u);
    return r >> 16;
}
static __device__ __forceinline__ __bf16 to_bf16(float f) {
    union { unsigned short s; __bf16 b; } y; y.s = (unsigned short)bfbits(f); return y.b;
}

// ---------------- prep 1: k/v projections of memory (tiny) ----------------
__global__ void prep_kv(const float* __restrict__ memory,
                        const float* __restrict__ Wk, const float* __restrict__ bk,
                        const float* __restrict__ Wv, const float* __restrict__ bv,
                        float* __restrict__ kproj, float* __restrict__ vproj) {
    __shared__ float mrow[DD];
    const int m = blockIdx.x;
    const int t = threadIdx.x;
    for (int i = t; i < DD; i += 256) mrow[i] = memory[(size_t)m * DD + i];
    __syncthreads();
    for (int jj = 0; jj < 2; ++jj) {
        const int j = t + jj * 256;
        const float* wkr = Wk + (size_t)j * DD;
        const float* wvr = Wv + (size_t)j * DD;
        float sk = 0.f, sv = 0.f;
        for (int d = 0; d < DD; ++d) {
            const float md = mrow[d];
            sk += md * wkr[d];
            sv += md * wvr[d];
        }
        kproj[(size_t)m * DD + j] = sk + bk[j];
        vproj[(size_t)m * DD + j] = sv + bv[j];
    }
}

// ---------------- prep 2: fold projections into W2t / b2 / W3t ----------------
// c = h*64 + m.
// W2t[c][d] = sum_hd Wq[h*64+hd, d] * kproj[m, h*64+hd]   (bf16, [512][512])
// b2[c]     = sum_hd bq[h*64+hd]    * kproj[m, h*64+hd]   (f32)
// W3t[j][c] = sum_hd vproj[m, h*64+hd] * Wo[j, h*64+hd]   (bf16, [512][512])
__global__ void prep_w(const float* __restrict__ Wq, const float* __restrict__ bq,
                       const float* __restrict__ Wo,
                       const float* __restrict__ kproj, const float* __restrict__ vproj,
                       __bf16* __restrict__ W2t, float* __restrict__ b2,
                       __bf16* __restrict__ W3t) {
    const int i = blockIdx.x;   // c for W2t/b2, j for W3t
    const int t = threadIdx.x;
    __shared__ float kp[HDIM];
    __shared__ float worow[DD];
    const int m = i & 63, h = i >> 6;
    if (t < HDIM) kp[t] = kproj[(size_t)m * DD + h * HDIM + t];
    for (int d = t; d < DD; d += 256) worow[d] = Wo[(size_t)i * DD + d];
    __syncthreads();
    for (int dd2 = 0; dd2 < 2; ++dd2) {
        const int d = t + dd2 * 256;
        float s = 0.f;
        #pragma unroll 8
        for (int hd = 0; hd < HDIM; ++hd)
            s += Wq[(size_t)(h * HDIM + hd) * DD + d] * kp[hd];
        W2t[(size_t)i * DD + d] = to_bf16(s);
    }
    if (t == 0) {
        float s = 0.f;
        for (int hd = 0; hd < HDIM; ++hd) s += bq[h * HDIM + hd] * kp[hd];
        b2[i] = s;
    }
    for (int cc = 0; cc < 2; ++cc) {
        const int c = t + cc * 256;
        const int mc = c & 63, hc = c >> 6;
        float s = 0.f;
        #pragma unroll 8
        for (int hd = 0; hd < HDIM; ++hd)
            s += vproj[(size_t)mc * DD + hc * HDIM + hd] * worow[hc * HDIM + hd];
        W3t[(size_t)i * DD + c] = to_bf16(s);
    }
}

// ---------------- kernel 1: S = x@W2 + b2, softmax -> attn (bf16) --------------
// 512 threads = 8 waves; wave w owns head w (cols w*64..w*64+63) for 32 rows.
// 32 KB LDS x-tile shared by all waves. 4 waves/SIMD occupancy target.
__global__ __launch_bounds__(512, 4) void k1_gemm_sm(
    const float* __restrict__ x, const int* __restrict__ mask,
    const __bf16* __restrict__ W2t, const float* __restrict__ b2,
    __bf16* __restrict__ attn, int row0) {
    __shared__ short xs[32 * 512];   // 32 KiB

    const int tid = threadIdx.x;
    const int lane = tid & 63;
    const int w = tid >> 6;          // 0..7 = head
    const int lc = lane & 15;
    const int grp = lane >> 4;
    const int lk = grp * 8;
    const int rl0 = blockIdx.x * 32;     // local (chunk) row base
    const int gr0 = row0 + rl0;          // global row base

    const __bf16* Bb = W2t + (size_t)(w * 64 + lc) * DD + lk;

    // hoist kt=0 B-fragments (independent of staging)
    bf16x8 bb[2][4];
    #pragma unroll
    for (int ct = 0; ct < 4; ++ct)
        bb[0][ct] = *(const bf16x8*)(Bb + (size_t)ct * 16 * DD);

    // stage 32x512 fp32 -> bf16 LDS (swizzled), non-temporal
    {
        const f32x4* xv = (const f32x4*)(x + (size_t)gr0 * DD);
        #pragma unroll
        for (int it = 0; it < 8; ++it) {
            const int idx4 = it * 512 + tid;
            const int row = idx4 >> 7;
            const int c4 = idx4 & 127;
            const f32x4 v = __builtin_nontemporal_load(xv + (size_t)row * 128 + c4);
            uint2 u;
            u.x = bfbits(v[0]) | (bfbits(v[1]) << 16);
            u.y = bfbits(v[2]) | (bfbits(v[3]) << 16);
            const int off = row * 1024 + ((c4 * 8) ^ ((row & 7) << 4));
            *(uint2*)((char*)xs + off) = u;
        }
    }
    __syncthreads();

    float b2v[4];
    #pragma unroll
    for (int ct = 0; ct < 4; ++ct) b2v[ct] = b2[w * 64 + ct * 16 + lc];

    #define LDA1(rt, k0) \
        (*(const bf16x8*)((const char*)xs + \
            ((rt) * 16 + lc) * 1024 + ((((k0) + lk) * 2) ^ ((((rt) * 16 + lc) & 7) << 4))))

    f32x4 acc[2][4];
    #pragma unroll
    for (int rt = 0; rt < 2; ++rt)
        #pragma unroll
        for (int ct = 0; ct < 4; ++ct)
            acc[rt][ct] = (f32x4){0.f, 0.f, 0.f, 0.f};

    bf16x8 aa[2][2];
    #pragma unroll
    for (int rt = 0; rt < 2; ++rt) aa[0][rt] = LDA1(rt, 0);

    #pragma unroll
    for (int kt = 0; kt < 16; ++kt) {
        const int cur = kt & 1, nxt = cur ^ 1;
        if (kt < 15) {
            const int k0n = (kt + 1) * 32;
            #pragma unroll
            for (int ct = 0; ct < 4; ++ct)
                bb[nxt][ct] = *(const bf16x8*)(Bb + (size_t)ct * 16 * DD + k0n);
            #pragma unroll
            for (int rt = 0; rt < 2; ++rt) aa[nxt][rt] = LDA1(rt, k0n);
        }
        __builtin_amdgcn_s_setprio(1);
        #pragma unroll
        for (int rt = 0; rt < 2; ++rt)
            #pragma unroll
            for (int ct = 0; ct < 4; ++ct)
                acc[rt][ct] = __builtin_amdgcn_mfma_f32_16x16x32_bf16(aa[cur][rt], bb[cur][ct], acc[rt][ct], 0, 0, 0);
        __builtin_amdgcn_s_setprio(0);
    }
    #undef LDA1

    // softmax over the wave's 64 cols (= head w), store attn bf16
    #pragma unroll
    for (int rt = 0; rt < 2; ++rt) {
        const int lr = rt * 16 + grp * 4;
        const int4 mv = *(const int4*)(mask + gr0 + lr);
        const int mk[4] = {mv.x, mv.y, mv.z, mv.w};
        #pragma unroll
        for (int j = 0; j < 4; ++j) {
            float s0 = (acc[rt][0][j] + b2v[0]) * 0.125f;
            float s1 = (acc[rt][1][j] + b2v[1]) * 0.125f;
            float s2 = (acc[rt][2][j] + b2v[2]) * 0.125f;
            float s3 = (acc[rt][3][j] + b2v[3]) * 0.125f;
            float mx = fmaxf(fmaxf(s0, s1), fmaxf(s2, s3));
            mx = fmaxf(mx, __shfl_xor(mx, 1));
            mx = fmaxf(mx, __shfl_xor(mx, 2));
            mx = fmaxf(mx, __shfl_xor(mx, 4));
            mx = fmaxf(mx, __shfl_xor(mx, 8));
            float p0 = __expf(s0 - mx);
            float p1 = __expf(s1 - mx);
            float p2 = __expf(s2 - mx);
            float p3 = __expf(s3 - mx);
            float sm = (p0 + p1) + (p2 + p3);
            sm += __shfl_xor(sm, 1);
            sm += __shfl_xor(sm, 2);
            sm += __shfl_xor(sm, 4);
            sm += __shfl_xor(sm, 8);
            float a0, a1, a2, a3;
            if (mk[j] == 0) {
                a0 = a1 = a2 = a3 = 0.015625f;   // fp32 -1e9 bias rounds to uniform attn
            } else {
                const float inv = 1.0f / sm;
                a0 = p0 * inv; a1 = p1 * inv; a2 = p2 * inv; a3 = p3 * inv;
            }
            __bf16* arow = attn + (size_t)(rl0 + lr + j) * DD + w * 64 + lc;
            arow[0]  = to_bf16(a0);
            arow[16] = to_bf16(a1);
            arow[32] = to_bf16(a2);
            arow[48] = to_bf16(a3);
        }
    }
}

// ---------------- kernel 2: out = attn@W3 + bo ----------------
// No LDS, no barriers: A (attn bf16) streamed as fragments from global.
// 256 threads = 4 waves; wave w owns cols (blockIdx.y*256 + w*64) for 32 rows.
__global__ __launch_bounds__(256, 4) void k2_gemm_out(
    const __bf16* __restrict__ attn, const __bf16* __restrict__ W3t,
    const float* __restrict__ bo, float* __restrict__ out, int row0) {
    const int tid = threadIdx.x;
    const int lane = tid & 63;
    const int w = tid >> 6;          // 0..3
    const int lc = lane & 15;
    const int grp = lane >> 4;
    const int lk = grp * 8;
    const int rl0 = blockIdx.x * 32;
    const int c0 = blockIdx.y * 256 + w * 64;

    const __bf16* Bb = W3t + (size_t)(c0 + lc) * DD + lk;
    const __bf16* Ab = attn + (size_t)(rl0 + lc) * DD + lk;

    bf16x8 bb[2][4];
    #pragma unroll
    for (int ct = 0; ct < 4; ++ct)
        bb[0][ct] = *(const bf16x8*)(Bb + (size_t)ct * 16 * DD);
    bf16x8 aa[2][2];
    #pragma unroll
    for (int rt = 0; rt < 2; ++rt)
        aa[0][rt] = *(const bf16x8*)(Ab + (size_t)rt * 16 * DD);

    f32x4 acc[2][4];
    #pragma unroll
    for (int rt = 0; rt < 2; ++rt)
        #pragma unroll
        for (int ct = 0; ct < 4; ++ct)
            acc[rt][ct] = (f32x4){0.f, 0.f, 0.f, 0.f};

    #pragma unroll
    for (int kt = 0; kt < 16; ++kt) {
        const int cur = kt & 1, nxt = cur ^ 1;
        if (kt < 15) {
            const int k0n = (kt + 1) * 32;
            #pragma unroll
            for (int ct = 0; ct < 4; ++ct)
                bb[nxt][ct] = *(const bf16x8*)(Bb + (size_t)ct * 16 * DD + k0n);
            #pragma unroll
            for (int rt = 0; rt < 2; ++rt)
                aa[nxt][rt] = *(const bf16x8*)(Ab + (size_t)rt * 16 * DD + k0n);
        }
        __builtin_amdgcn_s_setprio(1);
        #pragma unroll
        for (int rt = 0; rt < 2; ++rt)
            #pragma unroll
            for (int ct = 0; ct < 4; ++ct)
                acc[rt][ct] = __builtin_amdgcn_mfma_f32_16x16x32_bf16(aa[cur][rt], bb[cur][ct], acc[rt][ct], 0, 0, 0);
        __builtin_amdgcn_s_setprio(0);
    }

    float bov[4];
    #pragma unroll
    for (int ct = 0; ct < 4; ++ct) bov[ct] = bo[c0 + ct * 16 + lc];

    #pragma unroll
    for (int rt = 0; rt < 2; ++rt) {
        #pragma unroll
        for (int j = 0; j < 4; ++j) {
            const int gr = row0 + rl0 + rt * 16 + grp * 4 + j;
            float* orow = out + (size_t)gr * DD + c0 + lc;
            #pragma unroll
            for (int ct = 0; ct < 4; ++ct)
                __builtin_nontemporal_store(acc[rt][ct][j] + bov[ct], orow + ct * 16);
        }
    }
}

extern "C" void kernel_launch(void* const* d_in, const int* in_sizes, int n_in,
                              void* d_out, int out_size, void* d_ws, size_t ws_size,
                              hipStream_t stream) {
    const float* qf     = (const float*)d_in[0];
    const int*   mask   = (const int*)d_in[1];
    const float* memory = (const float*)d_in[2];
    const float* Wq     = (const float*)d_in[3];
    const float* bq     = (const float*)d_in[4];
    const float* Wk     = (const float*)d_in[5];
    const float* bk     = (const float*)d_in[6];
    const float* Wv     = (const float*)d_in[7];
    const float* bv     = (const float*)d_in[8];
    const float* Wo     = (const float*)d_in[9];
    const float* bo     = (const float*)d_in[10];

    char* ws = (char*)d_ws;
    float*  kproj = (float*)ws;                  // 128 KB
    float*  vproj = (float*)(ws + 131072);       // 128 KB
    float*  b2    = (float*)(ws + 262144);       // 2 KB
    __bf16* W2t   = (__bf16*)(ws + 264192);      // 512 KB
    __bf16* W3t   = (__bf16*)(ws + 788480);      // 512 KB
    __bf16* attn  = (__bf16*)(ws + 1572864);     // chunked intermediate

    // rows per chunk: limited by workspace, capped at 64 MB (L3 residency)
    size_t avail = ws_size > 1572864 ? ws_size - 1572864 : 0;
    long mr = (long)(avail / (DD * 2));
    int rpc = (int)((mr / 64) * 64);
    if (rpc > 65536) rpc = 65536;
    if (rpc < 64) rpc = 64;

    prep_kv<<<64, 256, 0, stream>>>(memory, Wk, bk, Wv, bv, kproj, vproj);
    prep_w<<<512, 256, 0, stream>>>(Wq, bq, Wo, kproj, vproj, W2t, b2, W3t);

    for (int row0 = 0; row0 < NROWS; row0 += rpc) {
        int rows = NROWS - row0; if (rows > rpc) rows = rpc;
        k1_gemm_sm<<<rows / 32, 512, 0, stream>>>(qf, mask, W2t, b2, attn, row0);
        k2_gemm_out<<<dim3(rows / 32, 2), 256, 0, stream>>>(attn, W3t, bo, (float*)d_out, row0);
    }
}

// Round 6
// 433.714 us; speedup vs baseline: 1.6576x; 1.6576x over previous
//
#include <hip/hip_runtime.h>
#include <hip/hip_bf16.h>

#define DD 512
#define HDIM 64
#define NROWS 131072

typedef __bf16 bf16x8 __attribute__((ext_vector_type(8)));
typedef float f32x4 __attribute__((ext_vector_type(4)));

static __device__ __forceinline__ unsigned bfbits(float f) {
    union { float f; unsigned u; } x; x.f = f;
    unsigned r = x.u + 0x7fffu + ((x.u >> 16) & 1u);
    return r >> 16;
}
static __device__ __forceinline__ __bf16 to_bf16(float f) {
    union { unsigned short s; __bf16 b; } y; y.s = (unsigned short)bfbits(f); return y.b;
}

// Element index inside an 8KB tile image: 128 "cols" x 32 k, two cols per 128B
// LDS line, XOR-swizzle on 16B granules -> ds_read_b128 frag reads are 2-way free.
static __device__ __forceinline__ int img_off(int colp, int kp) {
    return ((colp >> 1) * 64) + (((((colp) & 1) << 5) | (kp)) ^ (((colp >> 1) & 7) << 3));
}

static __device__ __forceinline__ void gll16(const void* gsrc, void* ldst) {
    __builtin_amdgcn_global_load_lds(
        (const __attribute__((address_space(1))) unsigned int*)gsrc,
        (__attribute__((address_space(3))) unsigned int*)ldst, 16, 0, 0);
}

// ---------------- prep 1: k/v projections of memory (tiny) ----------------
__global__ void prep_kv(const float* __restrict__ memory,
                        const float* __restrict__ Wk, const float* __restrict__ bk,
                        const float* __restrict__ Wv, const float* __restrict__ bv,
                        float* __restrict__ kproj, float* __restrict__ vproj) {
    __shared__ float mrow[DD];
    const int m = blockIdx.x;
    const int t = threadIdx.x;
    for (int i = t; i < DD; i += 256) mrow[i] = memory[(size_t)m * DD + i];
    __syncthreads();
    for (int jj = 0; jj < 2; ++jj) {
        const int j = t + jj * 256;
        const float* wkr = Wk + (size_t)j * DD;
        const float* wvr = Wv + (size_t)j * DD;
        float sk = 0.f, sv = 0.f;
        for (int d = 0; d < DD; ++d) {
            const float md = mrow[d];
            sk += md * wkr[d];
            sv += md * wvr[d];
        }
        kproj[(size_t)m * DD + j] = sk + bk[j];
        vproj[(size_t)m * DD + j] = sv + bv[j];
    }
}

// ---------------- prep 2: fold into W2f / b2 / W3f (tile-image layouts) -------
// c = h*64+m. W2 logical [col=c][k=d]; W3 logical [col=j][k=c].
// Image: tile (nt = col>>7, kt = k>>5), element img_off(col&127, k&31).
__global__ void prep_w(const float* __restrict__ Wq, const float* __restrict__ bq,
                       const float* __restrict__ Wo,
                       const float* __restrict__ kproj, const float* __restrict__ vproj,
                       __bf16* __restrict__ W2f, float* __restrict__ b2,
                       __bf16* __restrict__ W3f) {
    const int i = blockIdx.x;   // c for W2f/b2, j for W3f
    const int t = threadIdx.x;
    __shared__ float kp[HDIM];
    __shared__ float worow[DD];
    const int m = i & 63, h = i >> 6;
    if (t < HDIM) kp[t] = kproj[(size_t)m * DD + h * HDIM + t];
    for (int d = t; d < DD; d += 256) worow[d] = Wo[(size_t)i * DD + d];
    __syncthreads();
    for (int dd2 = 0; dd2 < 2; ++dd2) {
        const int d = t + dd2 * 256;
        float s = 0.f;
        #pragma unroll 8
        for (int hd = 0; hd < HDIM; ++hd)
            s += Wq[(size_t)(h * HDIM + hd) * DD + d] * kp[hd];
        W2f[(size_t)((i >> 7) * 16 + (d >> 5)) * 4096 + img_off(i & 127, d & 31)] = to_bf16(s);
    }
    if (t == 0) {
        float s = 0.f;
        for (int hd = 0; hd < HDIM; ++hd) s += bq[h * HDIM + hd] * kp[hd];
        b2[i] = s;
    }
    for (int cc = 0; cc < 2; ++cc) {
        const int c = t + cc * 256;
        const int mc = c & 63, hc = c >> 6;
        float s = 0.f;
        #pragma unroll 8
        for (int hd = 0; hd < HDIM; ++hd)
            s += vproj[(size_t)mc * DD + hc * HDIM + hd] * worow[hc * HDIM + hd];
        W3f[(size_t)((i >> 7) * 16 + (c >> 5)) * 4096 + img_off(i & 127, c & 31)] = to_bf16(s);
    }
}

// ---------------- kernel 1: S = x@W2 + b2, softmax -> attn_p tile images ------
// 128x128 tile, 4 waves (2x2), wave = 64 rows x 64 cols = one head slice.
__global__ __launch_bounds__(256, 2) void k1_gemm_sm(
    const float* __restrict__ x, const int* __restrict__ mask,
    const __bf16* __restrict__ W2f, const float* __restrict__ b2,
    __bf16* __restrict__ attn_p, int row0, int pstride) {
    __shared__ char ldsb[32768];   // A: 0/8192, B: 16384/24576

    const int tid = threadIdx.x;
    const int lane = tid & 63;
    const int wid = tid >> 6;            // 0..3
    const int wr = wid >> 1, wc = wid & 1;
    const int lc = lane & 15, grp = lane >> 4;
    const int rl0 = blockIdx.x * 128;
    const int nt = blockIdx.y;           // 0..3
    const int gr0 = row0 + rl0;
    const int hd = nt * 2 + wc;          // head owned by this wave

    const char* w2tile = (const char*)W2f + (size_t)nt * 16 * 8192;

    float b2v[4];
    #pragma unroll
    for (int n = 0; n < 4; ++n) b2v[n] = b2[hd * 64 + n * 16 + lc];

    f32x4 acc[4][4];
    #pragma unroll
    for (int m = 0; m < 4; ++m)
        #pragma unroll
        for (int n = 0; n < 4; ++n) acc[m][n] = (f32x4){0.f, 0.f, 0.f, 0.f};

    f32x4 xv[4];
    #define STAGE_A_LOAD(kt)                                                        \
        _Pragma("unroll")                                                           \
        for (int r = 0; r < 4; ++r) {                                               \
            const int qid = r * 256 + tid;                                          \
            const int row = qid >> 3, kq = qid & 7;                                 \
            xv[r] = __builtin_nontemporal_load(                                     \
                (const f32x4*)(x + (size_t)(gr0 + row) * DD + (kt) * 32 + kq * 4)); \
        }
    #define STAGE_A_WRITE(buf)                                                      \
        _Pragma("unroll")                                                           \
        for (int r = 0; r < 4; ++r) {                                               \
            const int qid = r * 256 + tid;                                          \
            const int row = qid >> 3, kq = qid & 7;                                 \
            uint2 u;                                                                \
            u.x = bfbits(xv[r][0]) | (bfbits(xv[r][1]) << 16);                      \
            u.y = bfbits(xv[r][2]) | (bfbits(xv[r][3]) << 16);                      \
            const int line = row >> 1;                                              \
            const int off = (buf) * 8192 + line * 128 +                             \
                (((((row) & 1) << 6) | (kq << 3)) ^ ((line & 7) << 4));             \
            *(uint2*)(ldsb + off) = u;                                              \
        }
    #define STAGE_B(kt, buf)                                                        \
        {                                                                           \
            const char* srcb = w2tile + (kt) * 8192 + wid * 1024 + lane * 16;       \
            char* dstb = ldsb + 16384 + (buf) * 8192 + wid * 1024;                  \
            gll16(srcb, dstb);                                                      \
            gll16(srcb + 4096, dstb + 4096);                                        \
        }

    #define LDA(buf, m) (*(const bf16x8*)(ldsb + (buf) * 8192 + 2 * img_off(wr * 64 + (m) * 16 + lc, grp * 8)))
    #define LDB(buf, n) (*(const bf16x8*)(ldsb + 16384 + (buf) * 8192 + 2 * img_off(wc * 64 + (n) * 16 + lc, grp * 8)))

    // prologue: stage kt=0 into buf 0
    STAGE_A_LOAD(0);
    STAGE_B(0, 0);
    STAGE_A_WRITE(0);
    __syncthreads();

    #pragma unroll 2
    for (int kt = 0; kt < 16; ++kt) {
        const int p = kt & 1;
        if (kt < 15) {
            STAGE_A_LOAD(kt + 1);
            STAGE_B(kt + 1, p ^ 1);
        }
        bf16x8 afr[4], bfr[4];
        #pragma unroll
        for (int m = 0; m < 4; ++m) afr[m] = LDA(p, m);
        #pragma unroll
        for (int n = 0; n < 4; ++n) bfr[n] = LDB(p, n);
        __builtin_amdgcn_s_setprio(1);
        #pragma unroll
        for (int m = 0; m < 4; ++m)
            #pragma unroll
            for (int n = 0; n < 4; ++n)
                acc[m][n] = __builtin_amdgcn_mfma_f32_16x16x32_bf16(afr[m], bfr[n], acc[m][n], 0, 0, 0);
        __builtin_amdgcn_s_setprio(0);
        if (kt < 15) STAGE_A_WRITE(p ^ 1);
        __syncthreads();
    }

    // ---- softmax (wave-local head) + repack into tile-image via own LDS region
    char* sreg = ldsb + wid * 8192;   // 2 slabs x 4KB (64 rows x 32 k each)
    #pragma unroll
    for (int m = 0; m < 4; ++m) {
        const int lr = m * 16 + grp * 4;
        const int4 mv = *(const int4*)(mask + gr0 + wr * 64 + lr);
        const int mk[4] = {mv.x, mv.y, mv.z, mv.w};
        #pragma unroll
        for (int j = 0; j < 4; ++j) {
            float s0 = (acc[m][0][j] + b2v[0]) * 0.125f;
            float s1 = (acc[m][1][j] + b2v[1]) * 0.125f;
            float s2 = (acc[m][2][j] + b2v[2]) * 0.125f;
            float s3 = (acc[m][3][j] + b2v[3]) * 0.125f;
            float mx = fmaxf(fmaxf(s0, s1), fmaxf(s2, s3));
            mx = fmaxf(mx, __shfl_xor(mx, 1));
            mx = fmaxf(mx, __shfl_xor(mx, 2));
            mx = fmaxf(mx, __shfl_xor(mx, 4));
            mx = fmaxf(mx, __shfl_xor(mx, 8));
            float p0 = __expf(s0 - mx);
            float p1 = __expf(s1 - mx);
            float p2 = __expf(s2 - mx);
            float p3 = __expf(s3 - mx);
            float sm = (p0 + p1) + (p2 + p3);
            sm += __shfl_xor(sm, 1);
            sm += __shfl_xor(sm, 2);
            sm += __shfl_xor(sm, 4);
            sm += __shfl_xor(sm, 8);
            float a0, a1, a2, a3;
            if (mk[j] == 0) {
                a0 = a1 = a2 = a3 = 0.015625f;   // fp32 -1e9 bias rounds to uniform attn
            } else {
                const float inv = 1.0f / sm;
                a0 = p0 * inv; a1 = p1 * inv; a2 = p2 * inv; a3 = p3 * inv;
            }
            const int row = lr + j;
            *(short*)(sreg + 0    + 2 * img_off(row, lc))      = (short)bfbits(a0);
            *(short*)(sreg + 0    + 2 * img_off(row, 16 + lc)) = (short)bfbits(a1);
            *(short*)(sreg + 4096 + 2 * img_off(row, lc))      = (short)bfbits(a2);
            *(short*)(sreg + 4096 + 2 * img_off(row, 16 + lc)) = (short)bfbits(a3);
        }
    }
    // wave-local readback (image is linear-copy) -> coalesced global stores
    const size_t slabbytes = (size_t)pstride * 64;
    #pragma unroll
    for (int s = 0; s < 2; ++s) {
        const int kt_a = hd * 2 + s;
        char* gdst = (char*)attn_p + (size_t)kt_a * slabbytes + (size_t)(rl0 + wr * 64) * 64;
        #pragma unroll
        for (int i = 0; i < 4; ++i) {
            bf16x8 v = *(const bf16x8*)(sreg + s * 4096 + i * 1024 + lane * 16);
            *(bf16x8*)(gdst + i * 1024 + lane * 16) = v;
        }
    }
    #undef STAGE_A_LOAD
    #undef STAGE_A_WRITE
    #undef STAGE_B
    #undef LDA
    #undef LDB
}

// ---------------- kernel 2: out = attn@W3 + bo --------------------------------
__global__ __launch_bounds__(256, 2) void k2_gemm_out(
    const __bf16* __restrict__ attn_p, const __bf16* __restrict__ W3f,
    const float* __restrict__ bo, float* __restrict__ out, int row0, int pstride) {
    __shared__ char ldsb[32768];

    const int tid = threadIdx.x;
    const int lane = tid & 63;
    const int wid = tid >> 6;
    const int wr = wid >> 1, wc = wid & 1;
    const int lc = lane & 15, grp = lane >> 4;
    const int rl0 = blockIdx.x * 128;
    const int nt = blockIdx.y;
    const size_t slabbytes = (size_t)pstride * 64;

    const char* w3tile = (const char*)W3f + (size_t)nt * 16 * 8192;
    const char* asrc0 = (const char*)attn_p + (size_t)rl0 * 64 + wid * 1024 + lane * 16;

    #define STAGE_A2(kt, buf)                                                      \
        {                                                                          \
            const char* srca = asrc0 + (size_t)(kt) * slabbytes;                   \
            char* dsta = ldsb + (buf) * 8192 + wid * 1024;                         \
            gll16(srca, dsta);                                                     \
            gll16(srca + 4096, dsta + 4096);                                       \
        }
    #define STAGE_B2(kt, buf)                                                      \
        {                                                                          \
            const char* srcb = w3tile + (kt) * 8192 + wid * 1024 + lane * 16;      \
            char* dstb = ldsb + 16384 + (buf) * 8192 + wid * 1024;                 \
            gll16(srcb, dstb);                                                     \
            gll16(srcb + 4096, dstb + 4096);                                       \
        }
    #define LDA(buf, m) (*(const bf16x8*)(ldsb + (buf) * 8192 + 2 * img_off(wr * 64 + (m) * 16 + lc, grp * 8)))
    #define LDB(buf, n) (*(const bf16x8*)(ldsb + 16384 + (buf) * 8192 + 2 * img_off(wc * 64 + (n) * 16 + lc, grp * 8)))

    f32x4 acc[4][4];
    #pragma unroll
    for (int m = 0; m < 4; ++m)
        #pragma unroll
        for (int n = 0; n < 4; ++n) acc[m][n] = (f32x4){0.f, 0.f, 0.f, 0.f};

    STAGE_A2(0, 0);
    STAGE_B2(0, 0);
    __syncthreads();

    #pragma unroll 2
    for (int kt = 0; kt < 16; ++kt) {
        const int p = kt & 1;
        if (kt < 15) {
            STAGE_A2(kt + 1, p ^ 1);
            STAGE_B2(kt + 1, p ^ 1);
        }
        bf16x8 afr[4], bfr[4];
        #pragma unroll
        for (int m = 0; m < 4; ++m) afr[m] = LDA(p, m);
        #pragma unroll
        for (int n = 0; n < 4; ++n) bfr[n] = LDB(p, n);
        __builtin_amdgcn_s_setprio(1);
        #pragma unroll
        for (int m = 0; m < 4; ++m)
            #pragma unroll
            for (int n = 0; n < 4; ++n)
                acc[m][n] = __builtin_amdgcn_mfma_f32_16x16x32_bf16(afr[m], bfr[n], acc[m][n], 0, 0, 0);
        __builtin_amdgcn_s_setprio(0);
        __syncthreads();
    }

    float bov[4];
    #pragma unroll
    for (int n = 0; n < 4; ++n) bov[n] = bo[nt * 128 + wc * 64 + n * 16 + lc];

    #pragma unroll
    for (int m = 0; m < 4; ++m) {
        #pragma unroll
        for (int j = 0; j < 4; ++j) {
            const int gr = row0 + rl0 + wr * 64 + m * 16 + grp * 4 + j;
            float* orow = out + (size_t)gr * DD + nt * 128 + wc * 64 + lc;
            #pragma unroll
            for (int n = 0; n < 4; ++n)
                __builtin_nontemporal_store(acc[m][n][j] + bov[n], orow + n * 16);
        }
    }
    #undef STAGE_A2
    #undef STAGE_B2
    #undef LDA
    #undef LDB
}

extern "C" void kernel_launch(void* const* d_in, const int* in_sizes, int n_in,
                              void* d_out, int out_size, void* d_ws, size_t ws_size,
                              hipStream_t stream) {
    const float* qf     = (const float*)d_in[0];
    const int*   mask   = (const int*)d_in[1];
    const float* memory = (const float*)d_in[2];
    const float* Wq     = (const float*)d_in[3];
    const float* bq     = (const float*)d_in[4];
    const float* Wk     = (const float*)d_in[5];
    const float* bk     = (const float*)d_in[6];
    const float* Wv     = (const float*)d_in[7];
    const float* bv     = (const float*)d_in[8];
    const float* Wo     = (const float*)d_in[9];
    const float* bo     = (const float*)d_in[10];

    char* ws = (char*)d_ws;
    float*  kproj = (float*)ws;                  // 128 KB
    float*  vproj = (float*)(ws + 131072);       // 128 KB
    float*  b2    = (float*)(ws + 262144);       // 2 KB
    __bf16* W2f   = (__bf16*)(ws + 264192);      // 512 KB
    __bf16* W3f   = (__bf16*)(ws + 788480);      // 512 KB
    __bf16* attn_p= (__bf16*)(ws + 1572864);     // chunked tile-image intermediate

    size_t avail = ws_size > 1572864 ? ws_size - 1572864 : 0;
    long mr = (long)(avail / (DD * 2));
    int rpc = (int)((mr / 128) * 128);
    if (rpc > 65536) rpc = 65536;
    if (rpc < 128) rpc = 128;

    prep_kv<<<64, 256, 0, stream>>>(memory, Wk, bk, Wv, bv, kproj, vproj);
    prep_w<<<512, 256, 0, stream>>>(Wq, bq, Wo, kproj, vproj, W2f, b2, W3f);

    for (int row0 = 0; row0 < NROWS; row0 += rpc) {
        int rows = NROWS - row0; if (rows > rpc) rows = rpc;
        k1_gemm_sm<<<dim3(rows / 128, 4), 256, 0, stream>>>(qf, mask, W2f, b2, attn_p, row0, rpc);
        k2_gemm_out<<<dim3(rows / 128, 4), 256, 0, stream>>>(attn_p, W3f, bo, (float*)d_out, row0, rpc);
    }
}

// Round 7
// 316.133 us; speedup vs baseline: 2.2741x; 1.3719x over previous
//
#include <hip/hip_runtime.h>
#include <hip/hip_bf16.h>

#define DD 512
#define HDIM 64
#define NROWS 131072

typedef __bf16 bf16x8 __attribute__((ext_vector_type(8)));
typedef float f32x4 __attribute__((ext_vector_type(4)));

static __device__ __forceinline__ unsigned bfbits(float f) {
    union { float f; unsigned u; } x; x.f = f;
    unsigned r = x.u + 0x7fffu + ((x.u >> 16) & 1u);
    return r >> 16;
}
static __device__ __forceinline__ __bf16 to_bf16(float f) {
    union { unsigned short s; __bf16 b; } y; y.s = (unsigned short)bfbits(f); return y.b;
}

// 8KB bf16 tile image: 128 cols x 32 k; two cols per 128B line, XOR swizzle on
// 16B granules -> ds_read_b128 fragment reads are 2-way (free).
static __device__ __forceinline__ int img_off(int colp, int kp) {
    return ((colp >> 1) * 64) + (((((colp) & 1) << 5) | (kp)) ^ (((colp >> 1) & 7) << 3));
}

static __device__ __forceinline__ void gll16(const void* gsrc, void* ldst) {
    __builtin_amdgcn_global_load_lds(
        (const __attribute__((address_space(1))) unsigned int*)gsrc,
        (__attribute__((address_space(3))) unsigned int*)ldst, 16, 0, 0);
}

#define VMCNT(n) asm volatile("s_waitcnt vmcnt(" #n ")" ::: "memory")

// bijective XCD-chunk swizzle (m204): co-locate consecutive swz ids per XCD
static __device__ __forceinline__ int xcd_swz(int bid, int nwg) {
    const int q = nwg >> 3, r = nwg & 7;
    const int xcd = bid & 7, idx = bid >> 3;
    return (xcd < r ? xcd * (q + 1) : r * (q + 1) + (xcd - r) * q) + idx;
}

// ---------------- prep 1: k/v projections of memory (tiny) ----------------
__global__ void prep_kv(const float* __restrict__ memory,
                        const float* __restrict__ Wk, const float* __restrict__ bk,
                        const float* __restrict__ Wv, const float* __restrict__ bv,
                        float* __restrict__ kproj, float* __restrict__ vproj) {
    __shared__ float mrow[DD];
    const int m = blockIdx.x;
    const int t = threadIdx.x;
    for (int i = t; i < DD; i += 256) mrow[i] = memory[(size_t)m * DD + i];
    __syncthreads();
    for (int jj = 0; jj < 2; ++jj) {
        const int j = t + jj * 256;
        const float* wkr = Wk + (size_t)j * DD;
        const float* wvr = Wv + (size_t)j * DD;
        float sk = 0.f, sv = 0.f;
        for (int d = 0; d < DD; ++d) {
            const float md = mrow[d];
            sk += md * wkr[d];
            sv += md * wvr[d];
        }
        kproj[(size_t)m * DD + j] = sk + bk[j];
        vproj[(size_t)m * DD + j] = sv + bv[j];
    }
}

// ---------------- prep 2: fold into W2f / b2 / W3f (tile-image layouts) -------
__global__ void prep_w(const float* __restrict__ Wq, const float* __restrict__ bq,
                       const float* __restrict__ Wo,
                       const float* __restrict__ kproj, const float* __restrict__ vproj,
                       __bf16* __restrict__ W2f, float* __restrict__ b2,
                       __bf16* __restrict__ W3f) {
    const int i = blockIdx.x;   // c for W2f/b2, j for W3f
    const int t = threadIdx.x;
    __shared__ float kp[HDIM];
    __shared__ float worow[DD];
    const int m = i & 63, h = i >> 6;
    if (t < HDIM) kp[t] = kproj[(size_t)m * DD + h * HDIM + t];
    for (int d = t; d < DD; d += 256) worow[d] = Wo[(size_t)i * DD + d];
    __syncthreads();
    for (int dd2 = 0; dd2 < 2; ++dd2) {
        const int d = t + dd2 * 256;
        float s = 0.f;
        #pragma unroll 8
        for (int hd = 0; hd < HDIM; ++hd)
            s += Wq[(size_t)(h * HDIM + hd) * DD + d] * kp[hd];
        W2f[(size_t)((i >> 7) * 16 + (d >> 5)) * 4096 + img_off(i & 127, d & 31)] = to_bf16(s);
    }
    if (t == 0) {
        float s = 0.f;
        for (int hd = 0; hd < HDIM; ++hd) s += bq[h * HDIM + hd] * kp[hd];
        b2[i] = s;
    }
    for (int cc = 0; cc < 2; ++cc) {
        const int c = t + cc * 256;
        const int mc = c & 63, hc = c >> 6;
        float s = 0.f;
        #pragma unroll 8
        for (int hd = 0; hd < HDIM; ++hd)
            s += vproj[(size_t)mc * DD + hc * HDIM + hd] * worow[hc * HDIM + hd];
        W3f[(size_t)((i >> 7) * 16 + (c >> 5)) * 4096 + img_off(i & 127, c & 31)] = to_bf16(s);
    }
}

// ---------------- kernel 1: S = x@W2 + b2, softmax -> attn_p tile images ------
// 128x128 tile, 4 waves (2x2). A staged fp32 via gll (inverse-swizzled source),
// cvt to bf16 at fragment read. Counted-vmcnt 2-barrier pipeline.
__global__ __launch_bounds__(256, 3) void k1_gemm_sm(
    const float* __restrict__ x, const int* __restrict__ mask,
    const __bf16* __restrict__ W2f, const float* __restrict__ b2,
    __bf16* __restrict__ attn_p, int row0, int pstride) {
    __shared__ char ldsb[49152];   // A fp32: 0/16384 (16KB each), B: 32768/40960

    const int tid = threadIdx.x;
    const int lane = tid & 63;
    const int wid = tid >> 6;
    const int wr = wid >> 1, wc = wid & 1;
    const int lc = lane & 15, grp = lane >> 4;
    const int swz = xcd_swz(blockIdx.x, gridDim.x);
    const int nt = swz & 3, rt = swz >> 2;
    const int rl0 = rt * 128;
    const int gr0 = row0 + rl0;
    const int hd = nt * 2 + wc;

    const char* w2tile = (const char*)W2f + (size_t)nt * 16 * 8192;
    const char* psB = w2tile + wid * 1024 + lane * 16;

    // A-gll per-lane source (inverse of the fp32 bank swizzle)
    const float* psA[4];
    #pragma unroll
    for (int i = 0; i < 4; ++i) {
        const int G = i * 256 + wid * 64 + lane;
        const int rowA = G >> 3;
        const int gA = (G & 7) ^ (rowA & 7);
        psA[i] = x + (size_t)(gr0 + rowA) * DD + gA * 4;
    }

    #define STAGE1(kt, buf)                                                       \
        {                                                                         \
            _Pragma("unroll")                                                     \
            for (int i = 0; i < 4; ++i)                                           \
                gll16(psA[i] + (kt) * 32, ldsb + (buf) * 16384 + i * 4096 + wid * 1024); \
            gll16(psB + (size_t)(kt) * 8192, ldsb + 32768 + (buf) * 8192 + wid * 1024); \
            gll16(psB + (size_t)(kt) * 8192 + 4096, ldsb + 32768 + (buf) * 8192 + 4096 + wid * 1024); \
        }

    f32x4 acc[4][4];
    #pragma unroll
    for (int m = 0; m < 4; ++m)
        #pragma unroll
        for (int n = 0; n < 4; ++n) acc[m][n] = (f32x4){0.f, 0.f, 0.f, 0.f};

    STAGE1(0, 0);

    #pragma unroll
    for (int kt = 0; kt < 16; ++kt) {
        const int p = kt & 1;
        if (kt < 15) {
            STAGE1(kt + 1, p ^ 1);
            VMCNT(6);
        } else {
            VMCNT(0);
        }
        __builtin_amdgcn_s_barrier();
        bf16x8 af[4], bfr[4];
        #pragma unroll
        for (int m = 0; m < 4; ++m) {
            const int row = wr * 64 + m * 16 + lc;
            const char* base = ldsb + p * 16384 + row * 128;
            const f32x4 lo = *(const f32x4*)(base + (((grp * 2) ^ (row & 7)) * 16));
            const f32x4 hi = *(const f32x4*)(base + (((grp * 2 + 1) ^ (row & 7)) * 16));
            bf16x8 v;
            v[0] = (__bf16)lo[0]; v[1] = (__bf16)lo[1]; v[2] = (__bf16)lo[2]; v[3] = (__bf16)lo[3];
            v[4] = (__bf16)hi[0]; v[5] = (__bf16)hi[1]; v[6] = (__bf16)hi[2]; v[7] = (__bf16)hi[3];
            af[m] = v;
        }
        #pragma unroll
        for (int n = 0; n < 4; ++n)
            bfr[n] = *(const bf16x8*)(ldsb + 32768 + p * 8192 + 2 * img_off(wc * 64 + n * 16 + lc, grp * 8));
        __builtin_amdgcn_s_setprio(1);
        #pragma unroll
        for (int m = 0; m < 4; ++m)
            #pragma unroll
            for (int n = 0; n < 4; ++n)
                acc[m][n] = __builtin_amdgcn_mfma_f32_16x16x32_bf16(af[m], bfr[n], acc[m][n], 0, 0, 0);
        __builtin_amdgcn_s_setprio(0);
        __builtin_amdgcn_s_barrier();
    }
    #undef STAGE1

    // ---- softmax (wave-local head) + repack into tile-image via own LDS region
    float b2v[4];
    #pragma unroll
    for (int n = 0; n < 4; ++n) b2v[n] = b2[hd * 64 + n * 16 + lc];

    char* sreg = ldsb + wid * 8192;   // 2 slabs x 4KB
    #pragma unroll
    for (int m = 0; m < 4; ++m) {
        const int lr = m * 16 + grp * 4;
        const int4 mv = *(const int4*)(mask + gr0 + wr * 64 + lr);
        const int mk[4] = {mv.x, mv.y, mv.z, mv.w};
        #pragma unroll
        for (int j = 0; j < 4; ++j) {
            float s0 = (acc[m][0][j] + b2v[0]) * 0.125f;
            float s1 = (acc[m][1][j] + b2v[1]) * 0.125f;
            float s2 = (acc[m][2][j] + b2v[2]) * 0.125f;
            float s3 = (acc[m][3][j] + b2v[3]) * 0.125f;
            float mx = fmaxf(fmaxf(s0, s1), fmaxf(s2, s3));
            mx = fmaxf(mx, __shfl_xor(mx, 1));
            mx = fmaxf(mx, __shfl_xor(mx, 2));
            mx = fmaxf(mx, __shfl_xor(mx, 4));
            mx = fmaxf(mx, __shfl_xor(mx, 8));
            float p0 = __expf(s0 - mx);
            float p1 = __expf(s1 - mx);
            float p2 = __expf(s2 - mx);
            float p3 = __expf(s3 - mx);
            float sm = (p0 + p1) + (p2 + p3);
            sm += __shfl_xor(sm, 1);
            sm += __shfl_xor(sm, 2);
            sm += __shfl_xor(sm, 4);
            sm += __shfl_xor(sm, 8);
            float a0, a1, a2, a3;
            if (mk[j] == 0) {
                a0 = a1 = a2 = a3 = 0.015625f;   // fp32 -1e9 bias rounds to uniform attn
            } else {
                const float inv = 1.0f / sm;
                a0 = p0 * inv; a1 = p1 * inv; a2 = p2 * inv; a3 = p3 * inv;
            }
            const int row = lr + j;
            *(short*)(sreg + 0    + 2 * img_off(row, lc))      = (short)bfbits(a0);
            *(short*)(sreg + 0    + 2 * img_off(row, 16 + lc)) = (short)bfbits(a1);
            *(short*)(sreg + 4096 + 2 * img_off(row, lc))      = (short)bfbits(a2);
            *(short*)(sreg + 4096 + 2 * img_off(row, 16 + lc)) = (short)bfbits(a3);
        }
    }
    const size_t slabbytes = (size_t)pstride * 64;
    #pragma unroll
    for (int s = 0; s < 2; ++s) {
        const int kt_a = hd * 2 + s;
        char* gdst = (char*)attn_p + (size_t)kt_a * slabbytes + (size_t)(rl0 + wr * 64) * 64;
        #pragma unroll
        for (int i = 0; i < 4; ++i) {
            bf16x8 v = *(const bf16x8*)(sreg + s * 4096 + i * 1024 + lane * 16);
            *(bf16x8*)(gdst + i * 1024 + lane * 16) = v;
        }
    }
}

// ---------------- kernel 2: out = attn@W3 + bo --------------------------------
__global__ __launch_bounds__(256, 3) void k2_gemm_out(
    const __bf16* __restrict__ attn_p, const __bf16* __restrict__ W3f,
    const float* __restrict__ bo, float* __restrict__ out, int row0, int pstride) {
    __shared__ char ldsb[32768];   // A: 0/8192, B: 16384/24576

    const int tid = threadIdx.x;
    const int lane = tid & 63;
    const int wid = tid >> 6;
    const int wr = wid >> 1, wc = wid & 1;
    const int lc = lane & 15, grp = lane >> 4;
    const int swz = xcd_swz(blockIdx.x, gridDim.x);
    const int nt = swz & 3, rt = swz >> 2;
    const int rl0 = rt * 128;
    const size_t slabbytes = (size_t)pstride * 64;

    const char* w3tile = (const char*)W3f + (size_t)nt * 16 * 8192;
    const char* psB = w3tile + wid * 1024 + lane * 16;
    const char* psA = (const char*)attn_p + (size_t)rl0 * 64 + wid * 1024 + lane * 16;

    #define STAGE2(kt, buf)                                                       \
        {                                                                         \
            gll16(psA + (size_t)(kt) * slabbytes, ldsb + (buf) * 8192 + wid * 1024); \
            gll16(psA + (size_t)(kt) * slabbytes + 4096, ldsb + (buf) * 8192 + 4096 + wid * 1024); \
            gll16(psB + (size_t)(kt) * 8192, ldsb + 16384 + (buf) * 8192 + wid * 1024); \
            gll16(psB + (size_t)(kt) * 8192 + 4096, ldsb + 16384 + (buf) * 8192 + 4096 + wid * 1024); \
        }

    f32x4 acc[4][4];
    #pragma unroll
    for (int m = 0; m < 4; ++m)
        #pragma unroll
        for (int n = 0; n < 4; ++n) acc[m][n] = (f32x4){0.f, 0.f, 0.f, 0.f};

    STAGE2(0, 0);

    #pragma unroll
    for (int kt = 0; kt < 16; ++kt) {
        const int p = kt & 1;
        if (kt < 15) {
            STAGE2(kt + 1, p ^ 1);
            VMCNT(4);
        } else {
            VMCNT(0);
        }
        __builtin_amdgcn_s_barrier();
        bf16x8 afr[4], bfr[4];
        #pragma unroll
        for (int m = 0; m < 4; ++m)
            afr[m] = *(const bf16x8*)(ldsb + p * 8192 + 2 * img_off(wr * 64 + m * 16 + lc, grp * 8));
        #pragma unroll
        for (int n = 0; n < 4; ++n)
            bfr[n] = *(const bf16x8*)(ldsb + 16384 + p * 8192 + 2 * img_off(wc * 64 + n * 16 + lc, grp * 8));
        __builtin_amdgcn_s_setprio(1);
        #pragma unroll
        for (int m = 0; m < 4; ++m)
            #pragma unroll
            for (int n = 0; n < 4; ++n)
                acc[m][n] = __builtin_amdgcn_mfma_f32_16x16x32_bf16(afr[m], bfr[n], acc[m][n], 0, 0, 0);
        __builtin_amdgcn_s_setprio(0);
        __builtin_amdgcn_s_barrier();
    }
    #undef STAGE2

    float bov[4];
    #pragma unroll
    for (int n = 0; n < 4; ++n) bov[n] = bo[nt * 128 + wc * 64 + n * 16 + lc];

    #pragma unroll
    for (int m = 0; m < 4; ++m) {
        #pragma unroll
        for (int j = 0; j < 4; ++j) {
            const int gr = row0 + rl0 + wr * 64 + m * 16 + grp * 4 + j;
            float* orow = out + (size_t)gr * DD + nt * 128 + wc * 64 + lc;
            #pragma unroll
            for (int n = 0; n < 4; ++n)
                __builtin_nontemporal_store(acc[m][n][j] + bov[n], orow + n * 16);
        }
    }
}

extern "C" void kernel_launch(void* const* d_in, const int* in_sizes, int n_in,
                              void* d_out, int out_size, void* d_ws, size_t ws_size,
                              hipStream_t stream) {
    const float* qf     = (const float*)d_in[0];
    const int*   mask   = (const int*)d_in[1];
    const float* memory = (const float*)d_in[2];
    const float* Wq     = (const float*)d_in[3];
    const float* bq     = (const float*)d_in[4];
    const float* Wk     = (const float*)d_in[5];
    const float* bk     = (const float*)d_in[6];
    const float* Wv     = (const float*)d_in[7];
    const float* bv     = (const float*)d_in[8];
    const float* Wo     = (const float*)d_in[9];
    const float* bo     = (const float*)d_in[10];

    char* ws = (char*)d_ws;
    float*  kproj = (float*)ws;                  // 128 KB
    float*  vproj = (float*)(ws + 131072);       // 128 KB
    float*  b2    = (float*)(ws + 262144);       // 2 KB
    __bf16* W2f   = (__bf16*)(ws + 264192);      // 512 KB
    __bf16* W3f   = (__bf16*)(ws + 788480);      // 512 KB
    __bf16* attn_p= (__bf16*)(ws + 1572864);     // tile-image intermediate

    // rows per chunk limited by workspace (attn image = rows*1024 B)
    size_t avail = ws_size > 1572864 ? ws_size - 1572864 : 0;
    long mr = (long)(avail / 1024);
    int rpc = (int)((mr / 128) * 128);
    if (rpc > NROWS) rpc = NROWS;
    if (rpc < 128) rpc = 128;

    prep_kv<<<64, 256, 0, stream>>>(memory, Wk, bk, Wv, bv, kproj, vproj);
    prep_w<<<512, 256, 0, stream>>>(Wq, bq, Wo, kproj, vproj, W2f, b2, W3f);

    for (int row0 = 0; row0 < NROWS; row0 += rpc) {
        int rows = NROWS - row0; if (rows > rpc) rows = rpc;
        const int nwg = (rows / 128) * 4;
        k1_gemm_sm<<<nwg, 256, 0, stream>>>(qf, mask, W2f, b2, attn_p, row0, rows);
        k2_gemm_out<<<nwg, 256, 0, stream>>>(attn_p, W3f, bo, (float*)d_out, row0, rows);
    }
}